// Round 8
// baseline (553.775 us; speedup 1.0000x reference)
//
#include <hip/hip_runtime.h>
#include <hip/hip_bf16.h>

#define LRELU(e) ((e) > 0.f ? (e) : 0.2f * (e))

typedef __attribute__((ext_vector_type(8))) short bf16x8;
typedef __attribute__((ext_vector_type(4))) float floatx4;

__device__ inline short f2bf(float f) {
    union { float f; unsigned u; } v; v.f = f;
    unsigned r = v.u + 0x7fffu + ((v.u >> 16) & 1u);
    return (short)(r >> 16);
}
__device__ inline float bflo(int p) {
    union { unsigned u; float f; } v; v.u = (unsigned)p << 16; return v.f;
}
__device__ inline float bfhi(int p) {
    union { unsigned u; float f; } v; v.u = (unsigned)p & 0xffff0000u; return v.f;
}
__device__ inline float bf2f(unsigned short s) {
    union { unsigned u; float f; } v; v.u = (unsigned)s << 16; return v.f;
}

// ---------------- CSR build (+ weight prep piggybacked) ----------------

__global__ void k_count_wprep(const int* __restrict__ dstE, int E, int N,
                              int* __restrict__ deg,
                              const float* __restrict__ W0, const float* __restrict__ W1,
                              const float* __restrict__ W2, short* __restrict__ Wt0,
                              short* __restrict__ Wt1, short* __restrict__ Wt2) {
    int i = blockIdx.x * blockDim.x + threadIdx.x;
    if (i < E) atomicAdd(&deg[dstE[i]], 1);
    else if (i < E + N) atomicAdd(&deg[i - E], 1);
    if (i < 128 * 128) {
        int n = i >> 7, k = i & 127;
        Wt0[i] = f2bf(W0[k * 128 + n]);
        Wt1[i] = f2bf(W1[k * 128 + n]);
    } else if (i < 128 * 128 + 64 * 128) {
        int j = i - 128 * 128;
        int n = j >> 7, k = j & 127;
        Wt2[j] = f2bf(W2[k * 64 + n]);
    }
}

constexpr int SC = 2048;

__global__ __launch_bounds__(256) void k_scan1(const int* __restrict__ deg, int N,
                                               int* __restrict__ partial) {
    int base = blockIdx.x * SC;
    int t = threadIdx.x;
    int s = 0;
    #pragma unroll
    for (int p = 0; p < SC / 256; p++) {
        int i = base + t + p * 256;
        if (i < N) s += deg[i];
    }
    #pragma unroll
    for (int off = 32; off; off >>= 1) s += __shfl_xor(s, off, 64);
    __shared__ int ws[4];
    int lane = t & 63, wid = t >> 6;
    if (lane == 0) ws[wid] = s;
    __syncthreads();
    if (t == 0) partial[blockIdx.x] = ws[0] + ws[1] + ws[2] + ws[3];
}

__global__ __launch_bounds__(256) void k_scan2(int* __restrict__ partial, int nb) {
    int t = threadIdx.x;
    int v = (t < nb) ? partial[t] : 0;
    int lane = t & 63, wid = t >> 6;
    int x = v;
    #pragma unroll
    for (int off = 1; off < 64; off <<= 1) {
        int y = __shfl_up(x, off, 64);
        if (lane >= off) x += y;
    }
    __shared__ int wsum[4];
    if (lane == 63) wsum[wid] = x;
    __syncthreads();
    int add = 0;
    for (int i = 0; i < wid; i++) add += wsum[i];
    if (t < nb) partial[t] = x + add - v;
}

__global__ __launch_bounds__(256) void k_scan3(const int* __restrict__ deg, int N, int Etot,
                                               const int* __restrict__ partial,
                                               int* __restrict__ rowptr,
                                               int* __restrict__ cursor) {
    int base = blockIdx.x * SC;
    int t = threadIdx.x;
    int i0 = base + t * 8;
    int v[8];
    int s = 0;
    #pragma unroll
    for (int p = 0; p < 8; p++) {
        int i = i0 + p;
        v[p] = (i < N) ? deg[i] : 0;
        s += v[p];
    }
    int lane = t & 63, wid = t >> 6;
    int x = s;
    #pragma unroll
    for (int off = 1; off < 64; off <<= 1) {
        int y = __shfl_up(x, off, 64);
        if (lane >= off) x += y;
    }
    __shared__ int wsum[4];
    if (lane == 63) wsum[wid] = x;
    __syncthreads();
    int add = 0;
    for (int i = 0; i < wid; i++) add += wsum[i];
    int excl = x - s + add + partial[blockIdx.x];
    #pragma unroll
    for (int p = 0; p < 8; p++) {
        int i = i0 + p;
        if (i < N) { rowptr[i] = excl; cursor[i] = excl; }
        excl += v[p];
    }
    if (blockIdx.x == 0 && t == 0) rowptr[N] = Etot;
}

__global__ void k_fill(const int* __restrict__ srcE, const int* __restrict__ dstE,
                       int E, int N, int* __restrict__ cursor, int* __restrict__ col,
                       int* __restrict__ dstarr) {
    int i = blockIdx.x * blockDim.x + threadIdx.x;
    if (i < E) {
        int d = dstE[i];
        int p = atomicAdd(&cursor[d], 1);
        col[p] = srcE[i];
        dstarr[p] = d;
    } else if (i < E + N) {
        int d = i - E;
        int p = atomicAdd(&cursor[d], 1);
        col[p] = d;
        dstarr[p] = d;
    }
}

// ---------------- MFMA bf16 GEMM + fused BN-apply + fused attention logits ----------
// HASBN: y = relu(X*scale+shift)+Xres replaces X. WRITEX: store y to Xout.
// Epilogue computes als/ald directly from accumulators (kills k_al/k_al2).

template <int DOUT, bool HASBN, bool WRITEX>
__global__ __launch_bounds__(256) void k_gemm(const float* __restrict__ X,
                                              const short* __restrict__ Wt,
                                              short* __restrict__ Hout,
                                              const float2* __restrict__ ss,
                                              const float* __restrict__ Xres,
                                              float* __restrict__ Xout,
                                              const float* __restrict__ a_s,
                                              const float* __restrict__ a_d,
                                              float* __restrict__ als,
                                              float* __restrict__ ald, int Nrows) {
    constexpr int KP = 136;
    constexpr int CT = DOUT / 16;
    __shared__ __align__(16) short Xs[128 * KP];
    __shared__ __align__(16) short Ws[DOUT * KP];

    const int tid = threadIdx.x;
    const int row0 = blockIdx.x * 128;

    {
        int c4 = tid & 31;
        int r0 = tid >> 5;
        float2 ssv[4];
        if (HASBN) {
            #pragma unroll
            for (int j = 0; j < 4; j++) ssv[j] = ss[c4 * 4 + j];
        }
        #pragma unroll
        for (int p = 0; p < 16; p++) {
            int r = r0 + p * 8;
            int grow = row0 + r;
            float4 v = make_float4(0.f, 0.f, 0.f, 0.f);
            float4 xr = make_float4(0.f, 0.f, 0.f, 0.f);
            if (grow < Nrows) {
                v = *(const float4*)&X[(size_t)grow * 128 + c4 * 4];
                if (HASBN) xr = *(const float4*)&Xres[(size_t)grow * 128 + c4 * 4];
            }
            if (HASBN) {
                float* vp = (float*)&v;
                float* xp = (float*)&xr;
                #pragma unroll
                for (int j = 0; j < 4; j++)
                    vp[j] = fmaxf(vp[j] * ssv[j].x + ssv[j].y, 0.f) + xp[j];
                if (WRITEX && grow < Nrows)
                    *(float4*)&Xout[(size_t)grow * 128 + c4 * 4] = v;
            }
            short4 b;
            b.x = f2bf(v.x); b.y = f2bf(v.y); b.z = f2bf(v.z); b.w = f2bf(v.w);
            *(short4*)&Xs[r * KP + c4 * 4] = b;
        }
    }
    {
        constexpr int UNITS = DOUT * 16;
        #pragma unroll
        for (int p = 0; p < UNITS / 256; p++) {
            int u = tid + p * 256;
            int n = u >> 4;
            int kc = (u & 15) * 8;
            bf16x8 v = *(const bf16x8*)&Wt[n * 128 + kc];
            *(bf16x8*)&Ws[n * KP + kc] = v;
        }
    }
    __syncthreads();

    const int lane = tid & 63;
    const int wv = tid >> 6;
    const int m0 = wv * 32;
    const int ln = lane & 15;
    const int quad = lane >> 4;

    floatx4 acc[2][CT];
    #pragma unroll
    for (int mt = 0; mt < 2; mt++)
        #pragma unroll
        for (int ct = 0; ct < CT; ct++) acc[mt][ct] = (floatx4){0.f, 0.f, 0.f, 0.f};

    #pragma unroll
    for (int ks = 0; ks < 4; ks++) {
        int ko = ks * 32 + quad * 8;
        bf16x8 a0 = *(const bf16x8*)&Xs[(m0 + ln) * KP + ko];
        bf16x8 a1 = *(const bf16x8*)&Xs[(m0 + 16 + ln) * KP + ko];
        #pragma unroll
        for (int ct = 0; ct < CT; ct++) {
            bf16x8 b = *(const bf16x8*)&Ws[(ct * 16 + ln) * KP + ko];
            acc[0][ct] = __builtin_amdgcn_mfma_f32_16x16x32_bf16(a0, b, acc[0][ct], 0, 0, 0);
            acc[1][ct] = __builtin_amdgcn_mfma_f32_16x16x32_bf16(a1, b, acc[1][ct], 0, 0, 0);
        }
    }

    // attention vectors for the fused logit computation
    float asv[CT], adv[CT];
    #pragma unroll
    for (int ct = 0; ct < CT; ct++) {
        asv[ct] = a_s[ct * 16 + ln];
        adv[ct] = a_d[ct * 16 + ln];
    }

    #pragma unroll
    for (int mt = 0; mt < 2; mt++) {
        #pragma unroll
        for (int r = 0; r < 4; r++) {
            int grow = row0 + m0 + mt * 16 + quad * 4 + r;
            if (grow < Nrows) {
                #pragma unroll
                for (int ct = 0; ct < CT; ct++)
                    Hout[(size_t)grow * DOUT + ct * 16 + ln] = f2bf(acc[mt][ct][r]);
            }
            if (DOUT == 128) {
                // per-head (ct) dot over d=ln: 8 separate 16-lane reductions
                float sh[CT], dh[CT];
                #pragma unroll
                for (int ct = 0; ct < CT; ct++) {
                    float val = acc[mt][ct][r];
                    sh[ct] = val * asv[ct];
                    dh[ct] = val * adv[ct];
                }
                #pragma unroll
                for (int off = 1; off < 16; off <<= 1) {
                    #pragma unroll
                    for (int ct = 0; ct < CT; ct++) {
                        sh[ct] += __shfl_xor(sh[ct], off, 16);
                        dh[ct] += __shfl_xor(dh[ct], off, 16);
                    }
                }
                if (grow < Nrows && ln < 8) {
                    float t0 = (ln & 1) ? sh[1] : sh[0];
                    float t1 = (ln & 1) ? sh[3] : sh[2];
                    float t2 = (ln & 1) ? sh[5] : sh[4];
                    float t3 = (ln & 1) ? sh[7] : sh[6];
                    float u0 = (ln & 2) ? t1 : t0;
                    float u1 = (ln & 2) ? t3 : t2;
                    float vs = (ln & 4) ? u1 : u0;
                    float d0 = (ln & 1) ? dh[1] : dh[0];
                    float d1 = (ln & 1) ? dh[3] : dh[2];
                    float d2 = (ln & 1) ? dh[5] : dh[4];
                    float d3 = (ln & 1) ? dh[7] : dh[6];
                    float e0 = (ln & 2) ? d1 : d0;
                    float e1 = (ln & 2) ? d3 : d2;
                    float vd = (ln & 4) ? e1 : e0;
                    als[grow * 8 + ln] = vs;
                    ald[grow * 8 + ln] = vd;
                }
            } else {
                // single head: total dot over all 64 dims
                float ssc = 0.f, ddc = 0.f;
                #pragma unroll
                for (int ct = 0; ct < CT; ct++) {
                    float val = acc[mt][ct][r];
                    ssc += val * asv[ct];
                    ddc += val * adv[ct];
                }
                #pragma unroll
                for (int off = 1; off < 16; off <<= 1) {
                    ssc += __shfl_xor(ssc, off, 16);
                    ddc += __shfl_xor(ddc, off, 16);
                }
                if (grow < Nrows && ln == 0) {
                    als[grow] = ssc;
                    ald[grow] = ddc;
                }
            }
        }
    }
}

// ---------------- per-edge softmax weights (unnormalized, bf16) ----------------

__global__ void k_edgew8(const int* __restrict__ col, const int* __restrict__ dstarr,
                         const float* __restrict__ als, const float* __restrict__ ald,
                         unsigned short* __restrict__ w16, int Etot) {
    int i = blockIdx.x * blockDim.x + threadIdx.x;
    if (i >= Etot * 8) return;
    int j = i >> 3, h = i & 7;
    int s = col[j], d = dstarr[j];
    float e = als[s * 8 + h] + ald[d * 8 + h];
    e = LRELU(e);
    w16[i] = (unsigned short)f2bf(__expf(e));
}

__global__ void k_edgew1(const int* __restrict__ col, const int* __restrict__ dstarr,
                         const float* __restrict__ als, const float* __restrict__ ald,
                         unsigned short* __restrict__ w16, int Etot) {
    int j = blockIdx.x * blockDim.x + threadIdx.x;
    if (j >= Etot) return;
    float e = als[col[j]] + ald[dstarr[j]];
    e = LRELU(e);
    w16[j] = (unsigned short)f2bf(__expf(e));
}

// ---------------- aggregate: 3 nodes per wave (interleaved) + fused BN stats ----------

__device__ inline void agg_drain(const int* __restrict__ col,
                                 const unsigned short* __restrict__ w16,
                                 const int* __restrict__ Hi, int lane, int h,
                                 int j, int end, float& s, float& a0, float& a1) {
    for (; j + 4 <= end; j += 4) {
        int c[4]; float ww[4]; int p[4];
        #pragma unroll
        for (int k = 0; k < 4; k++) c[k] = col[j + k];
        #pragma unroll
        for (int k = 0; k < 4; k++) {
            ww[k] = bf2f(w16[(j + k) * 8 + h]);
            p[k] = Hi[(c[k] << 6) + lane];
        }
        #pragma unroll
        for (int k = 0; k < 4; k++) {
            s += ww[k]; a0 += ww[k] * bflo(p[k]); a1 += ww[k] * bfhi(p[k]);
        }
    }
    for (; j < end; j++) {
        int c = col[j];
        float wv = bf2f(w16[j * 8 + h]);
        int p = Hi[(c << 6) + lane];
        s += wv; a0 += wv * bflo(p); a1 += wv * bfhi(p);
    }
}

__global__ __launch_bounds__(256) void k_agg(const int* __restrict__ rowptr,
                                             const int* __restrict__ col,
                                             const short* __restrict__ Hb,
                                             const unsigned short* __restrict__ w16,
                                             const float* __restrict__ bias,
                                             float* __restrict__ out,
                                             float* __restrict__ part, int N) {
    __shared__ float red[12][128];
    int wv = threadIdx.x >> 6;
    int lane = threadIdx.x & 63;
    int n0 = blockIdx.x * 12 + wv * 3;
    int n1 = n0 + 1, n2 = n0 + 2;
    int h = lane >> 3;
    const int* Hi = (const int*)Hb;
    bool v0 = n0 < N, v1 = n1 < N, v2 = n2 < N;
    int j0 = 0, e0 = 0, j1 = 0, e1 = 0, j2 = 0, e2 = 0;
    if (v0) { j0 = rowptr[n0]; e0 = rowptr[n0 + 1]; }
    if (v1) { j1 = rowptr[n1]; e1 = rowptr[n1 + 1]; }
    if (v2) { j2 = rowptr[n2]; e2 = rowptr[n2 + 1]; }
    float s0 = 0.f, x00 = 0.f, x01 = 0.f;
    float s1 = 0.f, x10 = 0.f, x11 = 0.f;
    float s2 = 0.f, x20 = 0.f, x21 = 0.f;

    // 12 independent H gathers in flight
    while (j0 + 4 <= e0 && j1 + 4 <= e1 && j2 + 4 <= e2) {
        int c[12];
        #pragma unroll
        for (int k = 0; k < 4; k++) {
            c[k] = col[j0 + k]; c[4 + k] = col[j1 + k]; c[8 + k] = col[j2 + k];
        }
        float ww[12]; int p[12];
        #pragma unroll
        for (int k = 0; k < 4; k++) {
            ww[k] = bf2f(w16[(j0 + k) * 8 + h]);
            ww[4 + k] = bf2f(w16[(j1 + k) * 8 + h]);
            ww[8 + k] = bf2f(w16[(j2 + k) * 8 + h]);
        }
        #pragma unroll
        for (int k = 0; k < 12; k++) p[k] = Hi[(c[k] << 6) + lane];
        #pragma unroll
        for (int k = 0; k < 4; k++) {
            s0 += ww[k];     x00 += ww[k] * bflo(p[k]);         x01 += ww[k] * bfhi(p[k]);
            s1 += ww[4 + k]; x10 += ww[4 + k] * bflo(p[4 + k]); x11 += ww[4 + k] * bfhi(p[4 + k]);
            s2 += ww[8 + k]; x20 += ww[8 + k] * bflo(p[8 + k]); x21 += ww[8 + k] * bfhi(p[8 + k]);
        }
        j0 += 4; j1 += 4; j2 += 4;
    }
    agg_drain(col, w16, Hi, lane, h, j0, e0, s0, x00, x01);
    agg_drain(col, w16, Hi, lane, h, j1, e1, s1, x10, x11);
    agg_drain(col, w16, Hi, lane, h, j2, e2, s2, x20, x21);

    float bx = bias[2 * lane], by = bias[2 * lane + 1];
    float2 o0 = make_float2(0.f, 0.f), o1 = make_float2(0.f, 0.f), o2 = make_float2(0.f, 0.f);
    if (v0) {
        float inv = 1.f / (s0 + 1e-16f);
        o0.x = x00 * inv + bx; o0.y = x01 * inv + by;
        ((float2*)out)[(size_t)n0 * 64 + lane] = o0;
    }
    if (v1) {
        float inv = 1.f / (s1 + 1e-16f);
        o1.x = x10 * inv + bx; o1.y = x11 * inv + by;
        ((float2*)out)[(size_t)n1 * 64 + lane] = o1;
    }
    if (v2) {
        float inv = 1.f / (s2 + 1e-16f);
        o2.x = x20 * inv + bx; o2.y = x21 * inv + by;
        ((float2*)out)[(size_t)n2 * 64 + lane] = o2;
    }
    red[wv * 3][2 * lane] = o0.x;     red[wv * 3][2 * lane + 1] = o0.y;
    red[wv * 3 + 1][2 * lane] = o1.x; red[wv * 3 + 1][2 * lane + 1] = o1.y;
    red[wv * 3 + 2][2 * lane] = o2.x; red[wv * 3 + 2][2 * lane + 1] = o2.y;
    __syncthreads();
    if (threadIdx.x < 128) {
        int c = threadIdx.x;
        float s = 0.f, q = 0.f;
        #pragma unroll
        for (int r = 0; r < 12; r++) {
            float v = red[r][c];
            s += v;
            q += v * v;
        }
        float* slot = part + (blockIdx.x & 63) * 256;
        atomicAdd(&slot[c], s);
        atomicAdd(&slot[128 + c], q);
    }
}

// ---------------- reduce partials -> (scale, shift); re-zero part for next layer ------

__global__ __launch_bounds__(128) void k_bnreduce(float* __restrict__ part,
                                                  const float* __restrict__ g,
                                                  const float* __restrict__ bt,
                                                  float invN, float2* __restrict__ ss) {
    int c = threadIdx.x;
    float s = 0.f, q = 0.f;
    #pragma unroll
    for (int k = 0; k < 64; k++) {
        s += part[k * 256 + c];
        q += part[k * 256 + 128 + c];
    }
    #pragma unroll
    for (int k = 0; k < 64; k++) {
        part[k * 256 + c] = 0.f;
        part[k * 256 + 128 + c] = 0.f;
    }
    float mu = s * invN;
    float var = q * invN - mu * mu;
    float scale = rsqrtf(var + 1e-5f) * g[c];
    ss[c] = make_float2(scale, bt[c] - mu * scale);
}

// ---------------- layer-2: 3 nodes per wave, aggregate + LayerNorm ----------------

__device__ inline void agg2_drain(const int* __restrict__ col,
                                  const unsigned short* __restrict__ w16,
                                  const unsigned short* __restrict__ H, int lane,
                                  int j, int end, float& s, float& a) {
    for (; j + 4 <= end; j += 4) {
        int c[4]; float ww[4]; unsigned short p[4];
        #pragma unroll
        for (int k = 0; k < 4; k++) c[k] = col[j + k];
        #pragma unroll
        for (int k = 0; k < 4; k++) {
            ww[k] = bf2f(w16[j + k]);
            p[k] = H[(c[k] << 6) + lane];
        }
        #pragma unroll
        for (int k = 0; k < 4; k++) { s += ww[k]; a += ww[k] * bf2f(p[k]); }
    }
    for (; j < end; j++) {
        int c = col[j];
        float wv = bf2f(w16[j]);
        s += wv; a += wv * bf2f(H[(c << 6) + lane]);
    }
}

__global__ __launch_bounds__(256) void k_agg2ln(const int* __restrict__ rowptr,
                                                const int* __restrict__ col,
                                                const short* __restrict__ Hb2,
                                                const unsigned short* __restrict__ w16,
                                                const float* __restrict__ b2,
                                                const float* __restrict__ lng,
                                                const float* __restrict__ lnb,
                                                float* __restrict__ out, int N) {
    int wv = threadIdx.x >> 6;
    int lane = threadIdx.x & 63;
    int n0 = blockIdx.x * 12 + wv * 3;
    int n1 = n0 + 1, n2 = n0 + 2;
    const unsigned short* H = (const unsigned short*)Hb2;
    bool v0 = n0 < N, v1 = n1 < N, v2 = n2 < N;
    int j0 = 0, e0 = 0, j1 = 0, e1 = 0, j2 = 0, e2 = 0;
    if (v0) { j0 = rowptr[n0]; e0 = rowptr[n0 + 1]; }
    if (v1) { j1 = rowptr[n1]; e1 = rowptr[n1 + 1]; }
    if (v2) { j2 = rowptr[n2]; e2 = rowptr[n2 + 1]; }
    float s0 = 0.f, a0 = 0.f, s1 = 0.f, a1 = 0.f, s2 = 0.f, a2 = 0.f;

    while (j0 + 4 <= e0 && j1 + 4 <= e1 && j2 + 4 <= e2) {
        int c[12];
        #pragma unroll
        for (int k = 0; k < 4; k++) {
            c[k] = col[j0 + k]; c[4 + k] = col[j1 + k]; c[8 + k] = col[j2 + k];
        }
        float ww[12]; unsigned short p[12];
        #pragma unroll
        for (int k = 0; k < 4; k++) {
            ww[k] = bf2f(w16[j0 + k]);
            ww[4 + k] = bf2f(w16[j1 + k]);
            ww[8 + k] = bf2f(w16[j2 + k]);
        }
        #pragma unroll
        for (int k = 0; k < 12; k++) p[k] = H[(c[k] << 6) + lane];
        #pragma unroll
        for (int k = 0; k < 4; k++) {
            s0 += ww[k];     a0 += ww[k] * bf2f(p[k]);
            s1 += ww[4 + k]; a1 += ww[4 + k] * bf2f(p[4 + k]);
            s2 += ww[8 + k]; a2 += ww[8 + k] * bf2f(p[8 + k]);
        }
        j0 += 4; j1 += 4; j2 += 4;
    }
    agg2_drain(col, w16, H, lane, j0, e0, s0, a0);
    agg2_drain(col, w16, H, lane, j1, e1, s1, a1);
    agg2_drain(col, w16, H, lane, j2, e2, s2, a2);

    float bv = b2[lane], gv = lng[lane], bb = lnb[lane];
    #pragma unroll
    for (int t = 0; t < 3; t++) {
        bool vd = t == 0 ? v0 : (t == 1 ? v1 : v2);
        float sx = t == 0 ? s0 : (t == 1 ? s1 : s2);
        float ax = t == 0 ? a0 : (t == 1 ? a1 : a2);
        int nd = n0 + t;
        float v = ax / (sx + 1e-16f) + bv;
        float su = v, sq = v * v;
        #pragma unroll
        for (int off = 32; off; off >>= 1) {
            su += __shfl_xor(su, off, 64);
            sq += __shfl_xor(sq, off, 64);
        }
        float mu = su * (1.f / 64.f);
        float var = sq * (1.f / 64.f) - mu * mu;
        float r = rsqrtf(var + 1e-5f);
        if (vd) out[(size_t)nd * 64 + lane] = (v - mu) * r * gv + bb;
    }
}

// ---------------- launch ----------------

extern "C" void kernel_launch(void* const* d_in, const int* in_sizes, int n_in,
                              void* d_out, int out_size, void* d_ws, size_t ws_size,
                              hipStream_t stream) {
    const float* x   = (const float*)d_in[0];
    const int*   ei  = (const int*)d_in[1];
    const float* W0  = (const float*)d_in[2];
    const float* as0 = (const float*)d_in[3];
    const float* ad0 = (const float*)d_in[4];
    const float* b0  = (const float*)d_in[5];
    const float* g0  = (const float*)d_in[6];
    const float* bt0 = (const float*)d_in[7];
    const float* W1  = (const float*)d_in[8];
    const float* as1 = (const float*)d_in[9];
    const float* ad1 = (const float*)d_in[10];
    const float* b1  = (const float*)d_in[11];
    const float* g1  = (const float*)d_in[12];
    const float* bt1 = (const float*)d_in[13];
    const float* W2  = (const float*)d_in[14];
    const float* as2 = (const float*)d_in[15];
    const float* ad2 = (const float*)d_in[16];
    const float* b2  = (const float*)d_in[17];
    const float* lng = (const float*)d_in[18];
    const float* lnb = (const float*)d_in[19];

    const int N = in_sizes[0] / 128;
    const int E = in_sizes[1] / 2;
    const int Etot = E + N;

    char* p = (char*)d_ws;
    auto carve = [&](size_t bytes) {
        void* q = (void*)p;
        p += (bytes + 255) & ~(size_t)255;
        return q;
    };
    short* Hb     = (short*)carve((size_t)N * 128 * 2);
    float* agg    = (float*)carve((size_t)N * 128 * 4);
    float* x1     = (float*)carve((size_t)N * 128 * 4);
    float* als    = (float*)carve((size_t)N * 8 * 4);
    float* ald    = (float*)carve((size_t)N * 8 * 4);
    int*   rowptr = (int*)carve((size_t)(N + 1) * 4);
    int*   cursor = (int*)carve((size_t)(N + 1) * 4);
    int*   deg    = (int*)carve((size_t)N * 4);
    int*   col    = (int*)carve((size_t)Etot * 4);
    int*   dstarr = (int*)carve((size_t)Etot * 4);
    unsigned short* w16 = (unsigned short*)carve((size_t)Etot * 8 * 2);
    float* part   = (float*)carve(64 * 256 * 4);
    float2* ss    = (float2*)carve(128 * 8);
    short* Wt0    = (short*)carve(128 * 128 * 2);
    short* Wt1    = (short*)carve(128 * 128 * 2);
    short* Wt2    = (short*)carve(64 * 128 * 2);
    int*   partial= (int*)carve(256 * 4);

    const float invN = 1.f / (float)N;
    const int eb = (E + N + 255) / 256;
    const int nsb = (N + SC - 1) / SC;

    // CSR build + weight prep
    hipMemsetAsync(deg, 0, (size_t)N * 4, stream);
    hipMemsetAsync(part, 0, 64 * 256 * 4, stream);
    k_count_wprep<<<eb, 256, 0, stream>>>(ei + E, E, N, deg, W0, W1, W2, Wt0, Wt1, Wt2);
    k_scan1<<<nsb, 256, 0, stream>>>(deg, N, partial);
    k_scan2<<<1, 256, 0, stream>>>(partial, nsb);
    k_scan3<<<nsb, 256, 0, stream>>>(deg, N, Etot, partial, rowptr, cursor);
    k_fill<<<eb, 256, 0, stream>>>(ei, ei + E, E, N, cursor, col, dstarr);

    const int gb = (N + 127) / 128;
    const int ab = (N + 11) / 12;
    const int ewb8 = (Etot * 8 + 255) / 256;
    const int ewb1 = (Etot + 255) / 256;

    // ---- layer 0 ----
    k_gemm<128, false, false><<<gb, 256, 0, stream>>>(x, Wt0, Hb, nullptr, nullptr, nullptr,
                                                      as0, ad0, als, ald, N);
    k_edgew8<<<ewb8, 256, 0, stream>>>(col, dstarr, als, ald, w16, Etot);
    k_agg<<<ab, 256, 0, stream>>>(rowptr, col, Hb, w16, b0, agg, part, N);
    k_bnreduce<<<1, 128, 0, stream>>>(part, g0, bt0, invN, ss);

    // ---- layer 1 (BN-apply fused into GEMM staging) ----
    k_gemm<128, true, true><<<gb, 256, 0, stream>>>(agg, Wt1, Hb, ss, x, x1,
                                                    as1, ad1, als, ald, N);
    k_edgew8<<<ewb8, 256, 0, stream>>>(col, dstarr, als, ald, w16, Etot);
    k_agg<<<ab, 256, 0, stream>>>(rowptr, col, Hb, w16, b1, agg, part, N);
    k_bnreduce<<<1, 128, 0, stream>>>(part, g1, bt1, invN, ss);

    // ---- layer 2 (BN-apply fused; x2 never materialized) ----
    k_gemm<64, true, false><<<gb, 256, 0, stream>>>(agg, Wt2, Hb, ss, x1, nullptr,
                                                    as2, ad2, als, ald, N);
    k_edgew1<<<ewb1, 256, 0, stream>>>(col, dstarr, als, ald, w16, Etot);
    k_agg2ln<<<ab, 256, 0, stream>>>(rowptr, col, Hb, w16, b2, lng, lnb, (float*)d_out, N);
}

// Round 9
// 509.762 us; speedup vs baseline: 1.0863x; 1.0863x over previous
//
#include <hip/hip_runtime.h>
#include <hip/hip_bf16.h>

#define LRELU(e) ((e) > 0.f ? (e) : 0.2f * (e))

typedef __attribute__((ext_vector_type(8))) short bf16x8;
typedef __attribute__((ext_vector_type(4))) float floatx4;

__device__ inline short f2bf(float f) {
    union { float f; unsigned u; } v; v.f = f;
    unsigned r = v.u + 0x7fffu + ((v.u >> 16) & 1u);
    return (short)(r >> 16);
}
__device__ inline float bflo(int p) {
    union { unsigned u; float f; } v; v.u = (unsigned)p << 16; return v.f;
}
__device__ inline float bfhi(int p) {
    union { unsigned u; float f; } v; v.u = (unsigned)p & 0xffff0000u; return v.f;
}
__device__ inline float bf2f(unsigned short s) {
    union { unsigned u; float f; } v; v.u = (unsigned)s << 16; return v.f;
}

// ---------------- CSR build + weight prep (incl. folded attention columns) ----------
// Wt layout: [DOUT+16][128] transposed bf16. Rows DOUT..DOUT+7 = W·a_s per head,
// rows DOUT+8..DOUT+15 = W·a_d per head (layer2: rows 64/65, rest unused).

__global__ void k_count_wprep(const int* __restrict__ dstE, int E, int N,
                              int* __restrict__ deg,
                              const float* __restrict__ W0, const float* __restrict__ W1,
                              const float* __restrict__ W2,
                              const float* __restrict__ as0, const float* __restrict__ ad0,
                              const float* __restrict__ as1, const float* __restrict__ ad1,
                              const float* __restrict__ as2, const float* __restrict__ ad2,
                              short* __restrict__ Wt0, short* __restrict__ Wt1,
                              short* __restrict__ Wt2) {
    int i = blockIdx.x * blockDim.x + threadIdx.x;
    if (i < E) atomicAdd(&deg[dstE[i]], 1);
    else if (i < E + N) atomicAdd(&deg[i - E], 1);

    if (i < 128 * 128) {
        int n = i >> 7, k = i & 127;
        Wt0[n * 128 + k] = f2bf(W0[k * 128 + n]);
        Wt1[n * 128 + k] = f2bf(W1[k * 128 + n]);
    } else if (i < 128 * 128 + 64 * 128) {
        int j = i - 128 * 128;
        int n = j >> 7, k = j & 127;
        Wt2[n * 128 + k] = f2bf(W2[k * 64 + n]);
    } else if (i < 128 * 128 + 64 * 128 + 128 * 8) {
        // augmented rows for layers 0/1: per (k, h) 16-dot
        int j = i - (128 * 128 + 64 * 128);
        int k = j >> 3, h = j & 7;
        float s0 = 0.f, d0 = 0.f, s1 = 0.f, d1 = 0.f;
        #pragma unroll
        for (int d = 0; d < 16; d++) {
            float w0 = W0[k * 128 + h * 16 + d];
            float w1 = W1[k * 128 + h * 16 + d];
            s0 += w0 * as0[h * 16 + d];
            d0 += w0 * ad0[h * 16 + d];
            s1 += w1 * as1[h * 16 + d];
            d1 += w1 * ad1[h * 16 + d];
        }
        Wt0[(128 + h) * 128 + k] = f2bf(s0);
        Wt0[(136 + h) * 128 + k] = f2bf(d0);
        Wt1[(128 + h) * 128 + k] = f2bf(s1);
        Wt1[(136 + h) * 128 + k] = f2bf(d1);
    } else if (i < 128 * 128 + 64 * 128 + 128 * 8 + 128) {
        // layer-2 augmented rows (single head, 64-dot) + zero unused rows
        int k = i - (128 * 128 + 64 * 128 + 128 * 8);
        float s = 0.f, d = 0.f;
        #pragma unroll
        for (int dd = 0; dd < 64; dd++) {
            float w = W2[k * 64 + dd];
            s += w * as2[dd];
            d += w * ad2[dd];
        }
        Wt2[64 * 128 + k] = f2bf(s);
        Wt2[65 * 128 + k] = f2bf(d);
        #pragma unroll
        for (int r = 66; r < 80; r++) Wt2[r * 128 + k] = 0;
    }
}

constexpr int SC = 2048;

__global__ __launch_bounds__(256) void k_scan1(const int* __restrict__ deg, int N,
                                               int* __restrict__ partial) {
    int base = blockIdx.x * SC;
    int t = threadIdx.x;
    int s = 0;
    #pragma unroll
    for (int p = 0; p < SC / 256; p++) {
        int i = base + t + p * 256;
        if (i < N) s += deg[i];
    }
    #pragma unroll
    for (int off = 32; off; off >>= 1) s += __shfl_xor(s, off, 64);
    __shared__ int ws[4];
    int lane = t & 63, wid = t >> 6;
    if (lane == 0) ws[wid] = s;
    __syncthreads();
    if (t == 0) partial[blockIdx.x] = ws[0] + ws[1] + ws[2] + ws[3];
}

__global__ __launch_bounds__(256) void k_scan2(int* __restrict__ partial, int nb) {
    int t = threadIdx.x;
    int v = (t < nb) ? partial[t] : 0;
    int lane = t & 63, wid = t >> 6;
    int x = v;
    #pragma unroll
    for (int off = 1; off < 64; off <<= 1) {
        int y = __shfl_up(x, off, 64);
        if (lane >= off) x += y;
    }
    __shared__ int wsum[4];
    if (lane == 63) wsum[wid] = x;
    __syncthreads();
    int add = 0;
    for (int i = 0; i < wid; i++) add += wsum[i];
    if (t < nb) partial[t] = x + add - v;
}

__global__ __launch_bounds__(256) void k_scan3(const int* __restrict__ deg, int N, int Etot,
                                               const int* __restrict__ partial,
                                               int* __restrict__ rowptr,
                                               int* __restrict__ cursor) {
    int base = blockIdx.x * SC;
    int t = threadIdx.x;
    int i0 = base + t * 8;
    int v[8];
    int s = 0;
    #pragma unroll
    for (int p = 0; p < 8; p++) {
        int i = i0 + p;
        v[p] = (i < N) ? deg[i] : 0;
        s += v[p];
    }
    int lane = t & 63, wid = t >> 6;
    int x = s;
    #pragma unroll
    for (int off = 1; off < 64; off <<= 1) {
        int y = __shfl_up(x, off, 64);
        if (lane >= off) x += y;
    }
    __shared__ int wsum[4];
    if (lane == 63) wsum[wid] = x;
    __syncthreads();
    int add = 0;
    for (int i = 0; i < wid; i++) add += wsum[i];
    int excl = x - s + add + partial[blockIdx.x];
    #pragma unroll
    for (int p = 0; p < 8; p++) {
        int i = i0 + p;
        if (i < N) { rowptr[i] = excl; cursor[i] = excl; }
        excl += v[p];
    }
    if (blockIdx.x == 0 && t == 0) rowptr[N] = Etot;
}

__global__ void k_fill(const int* __restrict__ srcE, const int* __restrict__ dstE,
                       int E, int N, int* __restrict__ cursor, int* __restrict__ col,
                       int* __restrict__ dstarr) {
    int i = blockIdx.x * blockDim.x + threadIdx.x;
    if (i < E) {
        int d = dstE[i];
        int p = atomicAdd(&cursor[d], 1);
        col[p] = srcE[i];
        dstarr[p] = d;
    } else if (i < E + N) {
        int d = i - E;
        int p = atomicAdd(&cursor[d], 1);
        col[p] = d;
        dstarr[p] = d;
    }
}

// ---------------- MFMA bf16 GEMM + fused BN-apply; logits via augmented columns -------

template <int DOUT, bool HASBN, bool WRITEX>
__global__ __launch_bounds__(256) void k_gemm(const float* __restrict__ X,
                                              const short* __restrict__ Wt,
                                              short* __restrict__ Hout,
                                              const float2* __restrict__ ss,
                                              const float* __restrict__ Xres,
                                              float* __restrict__ Xout,
                                              float* __restrict__ als,
                                              float* __restrict__ ald, int Nrows) {
    constexpr int KP = 136;
    constexpr int CT = DOUT / 16;       // H col tiles
    constexpr int CTT = CT + 1;         // + augmented logit tile
    __shared__ __align__(16) short Xs[128 * KP];
    __shared__ __align__(16) short Ws[(DOUT + 16) * KP];

    const int tid = threadIdx.x;
    const int row0 = blockIdx.x * 128;

    {
        int c4 = tid & 31;
        int r0 = tid >> 5;
        float2 ssv[4];
        if (HASBN) {
            #pragma unroll
            for (int j = 0; j < 4; j++) ssv[j] = ss[c4 * 4 + j];
        }
        #pragma unroll
        for (int p = 0; p < 16; p++) {
            int r = r0 + p * 8;
            int grow = row0 + r;
            float4 v = make_float4(0.f, 0.f, 0.f, 0.f);
            float4 xr = make_float4(0.f, 0.f, 0.f, 0.f);
            if (grow < Nrows) {
                v = *(const float4*)&X[(size_t)grow * 128 + c4 * 4];
                if (HASBN) xr = *(const float4*)&Xres[(size_t)grow * 128 + c4 * 4];
            }
            if (HASBN) {
                float* vp = (float*)&v;
                float* xp = (float*)&xr;
                #pragma unroll
                for (int j = 0; j < 4; j++)
                    vp[j] = fmaxf(vp[j] * ssv[j].x + ssv[j].y, 0.f) + xp[j];
                if (WRITEX && grow < Nrows)
                    *(float4*)&Xout[(size_t)grow * 128 + c4 * 4] = v;
            }
            short4 b;
            b.x = f2bf(v.x); b.y = f2bf(v.y); b.z = f2bf(v.z); b.w = f2bf(v.w);
            *(short4*)&Xs[r * KP + c4 * 4] = b;
        }
    }
    {
        constexpr int UNITS = (DOUT + 16) * 16;
        #pragma unroll
        for (int p = 0; p < UNITS / 256; p++) {
            int u = tid + p * 256;
            int n = u >> 4;
            int kc = (u & 15) * 8;
            bf16x8 v = *(const bf16x8*)&Wt[n * 128 + kc];
            *(bf16x8*)&Ws[n * KP + kc] = v;
        }
    }
    __syncthreads();

    const int lane = tid & 63;
    const int wv = tid >> 6;
    const int m0 = wv * 32;
    const int ln = lane & 15;
    const int quad = lane >> 4;

    floatx4 acc[2][CTT];
    #pragma unroll
    for (int mt = 0; mt < 2; mt++)
        #pragma unroll
        for (int ct = 0; ct < CTT; ct++) acc[mt][ct] = (floatx4){0.f, 0.f, 0.f, 0.f};

    #pragma unroll
    for (int ks = 0; ks < 4; ks++) {
        int ko = ks * 32 + quad * 8;
        bf16x8 a0 = *(const bf16x8*)&Xs[(m0 + ln) * KP + ko];
        bf16x8 a1 = *(const bf16x8*)&Xs[(m0 + 16 + ln) * KP + ko];
        #pragma unroll
        for (int ct = 0; ct < CTT; ct++) {
            bf16x8 b = *(const bf16x8*)&Ws[(ct * 16 + ln) * KP + ko];
            acc[0][ct] = __builtin_amdgcn_mfma_f32_16x16x32_bf16(a0, b, acc[0][ct], 0, 0, 0);
            acc[1][ct] = __builtin_amdgcn_mfma_f32_16x16x32_bf16(a1, b, acc[1][ct], 0, 0, 0);
        }
    }

    #pragma unroll
    for (int mt = 0; mt < 2; mt++) {
        #pragma unroll
        for (int r = 0; r < 4; r++) {
            int grow = row0 + m0 + mt * 16 + quad * 4 + r;
            if (grow < Nrows) {
                #pragma unroll
                for (int ct = 0; ct < CT; ct++)
                    Hout[(size_t)grow * DOUT + ct * 16 + ln] = f2bf(acc[mt][ct][r]);
                float aug = acc[mt][CT][r];
                if (DOUT == 128) {
                    if (ln < 8) als[grow * 8 + ln] = aug;
                    else        ald[grow * 8 + (ln - 8)] = aug;
                } else {
                    if (ln == 0) als[grow] = aug;
                    else if (ln == 1) ald[grow] = aug;
                }
            }
        }
    }
}

// ---------------- per-edge softmax weights (unnormalized, bf16) ----------------

__global__ void k_edgew8(const int* __restrict__ col, const int* __restrict__ dstarr,
                         const float* __restrict__ als, const float* __restrict__ ald,
                         unsigned short* __restrict__ w16, int Etot) {
    int i = blockIdx.x * blockDim.x + threadIdx.x;
    if (i >= Etot * 8) return;
    int j = i >> 3, h = i & 7;
    int s = col[j], d = dstarr[j];
    float e = als[s * 8 + h] + ald[d * 8 + h];
    e = LRELU(e);
    w16[i] = (unsigned short)f2bf(__expf(e));
}

__global__ void k_edgew1(const int* __restrict__ col, const int* __restrict__ dstarr,
                         const float* __restrict__ als, const float* __restrict__ ald,
                         unsigned short* __restrict__ w16, int Etot) {
    int j = blockIdx.x * blockDim.x + threadIdx.x;
    if (j >= Etot) return;
    float e = als[col[j]] + ald[dstarr[j]];
    e = LRELU(e);
    w16[j] = (unsigned short)f2bf(__expf(e));
}

// ---------------- aggregate: 2 nodes per wave (interleaved) + fused BN stats ----------

__global__ __launch_bounds__(256) void k_agg(const int* __restrict__ rowptr,
                                             const int* __restrict__ col,
                                             const short* __restrict__ Hb,
                                             const unsigned short* __restrict__ w16,
                                             const float* __restrict__ bias,
                                             float* __restrict__ out,
                                             float* __restrict__ part, int N) {
    __shared__ float red[8][128];
    int wv = threadIdx.x >> 6;
    int lane = threadIdx.x & 63;
    int nodeA = blockIdx.x * 8 + wv * 2;
    int nodeB = nodeA + 1;
    int h = lane >> 3;
    const int* Hi = (const int*)Hb;
    bool vA = nodeA < N, vB = nodeB < N;
    int jA = 0, endA = 0, jB = 0, endB = 0;
    if (vA) { jA = rowptr[nodeA]; endA = rowptr[nodeA + 1]; }
    if (vB) { jB = rowptr[nodeB]; endB = rowptr[nodeB + 1]; }
    float sA = 0.f, a0A = 0.f, a1A = 0.f;
    float sB = 0.f, a0B = 0.f, a1B = 0.f;

    while (jA + 4 <= endA && jB + 4 <= endB) {
        int c[8];
        #pragma unroll
        for (int k = 0; k < 4; k++) { c[k] = col[jA + k]; c[4 + k] = col[jB + k]; }
        float ww[8];
        int p[8];
        #pragma unroll
        for (int k = 0; k < 4; k++) {
            ww[k] = bf2f(w16[(jA + k) * 8 + h]);
            ww[4 + k] = bf2f(w16[(jB + k) * 8 + h]);
            p[k] = Hi[(c[k] << 6) + lane];
            p[4 + k] = Hi[(c[4 + k] << 6) + lane];
        }
        #pragma unroll
        for (int k = 0; k < 4; k++) {
            sA += ww[k];     a0A += ww[k] * bflo(p[k]);         a1A += ww[k] * bfhi(p[k]);
            sB += ww[4 + k]; a0B += ww[4 + k] * bflo(p[4 + k]); a1B += ww[4 + k] * bfhi(p[4 + k]);
        }
        jA += 4; jB += 4;
    }
    for (; jA + 4 <= endA; jA += 4) {
        int c[4]; float ww[4]; int p[4];
        #pragma unroll
        for (int k = 0; k < 4; k++) c[k] = col[jA + k];
        #pragma unroll
        for (int k = 0; k < 4; k++) { ww[k] = bf2f(w16[(jA + k) * 8 + h]); p[k] = Hi[(c[k] << 6) + lane]; }
        #pragma unroll
        for (int k = 0; k < 4; k++) { sA += ww[k]; a0A += ww[k] * bflo(p[k]); a1A += ww[k] * bfhi(p[k]); }
    }
    for (; jA < endA; jA++) {
        int cc = col[jA];
        float wv2 = bf2f(w16[jA * 8 + h]);
        int pp = Hi[(cc << 6) + lane];
        sA += wv2; a0A += wv2 * bflo(pp); a1A += wv2 * bfhi(pp);
    }
    for (; jB + 4 <= endB; jB += 4) {
        int c[4]; float ww[4]; int p[4];
        #pragma unroll
        for (int k = 0; k < 4; k++) c[k] = col[jB + k];
        #pragma unroll
        for (int k = 0; k < 4; k++) { ww[k] = bf2f(w16[(jB + k) * 8 + h]); p[k] = Hi[(c[k] << 6) + lane]; }
        #pragma unroll
        for (int k = 0; k < 4; k++) { sB += ww[k]; a0B += ww[k] * bflo(p[k]); a1B += ww[k] * bfhi(p[k]); }
    }
    for (; jB < endB; jB++) {
        int cc = col[jB];
        float wv2 = bf2f(w16[jB * 8 + h]);
        int pp = Hi[(cc << 6) + lane];
        sB += wv2; a0B += wv2 * bflo(pp); a1B += wv2 * bfhi(pp);
    }

    float2 oA = make_float2(0.f, 0.f), oB = make_float2(0.f, 0.f);
    if (vA) {
        float inv = 1.f / (sA + 1e-16f);
        oA.x = a0A * inv + bias[2 * lane];
        oA.y = a1A * inv + bias[2 * lane + 1];
        ((float2*)out)[(size_t)nodeA * 64 + lane] = oA;
    }
    if (vB) {
        float inv = 1.f / (sB + 1e-16f);
        oB.x = a0B * inv + bias[2 * lane];
        oB.y = a1B * inv + bias[2 * lane + 1];
        ((float2*)out)[(size_t)nodeB * 64 + lane] = oB;
    }
    red[wv * 2][2 * lane] = oA.x;
    red[wv * 2][2 * lane + 1] = oA.y;
    red[wv * 2 + 1][2 * lane] = oB.x;
    red[wv * 2 + 1][2 * lane + 1] = oB.y;
    __syncthreads();
    if (threadIdx.x < 128) {
        int c = threadIdx.x;
        float s = 0.f, q = 0.f;
        #pragma unroll
        for (int r = 0; r < 8; r++) {
            float v = red[r][c];
            s += v;
            q += v * v;
        }
        float* slot = part + (blockIdx.x & 63) * 256;
        atomicAdd(&slot[c], s);
        atomicAdd(&slot[128 + c], q);
    }
}

// ---------------- reduce partials -> (scale, shift); re-zero part ----------------

__global__ __launch_bounds__(128) void k_bnreduce(float* __restrict__ part,
                                                  const float* __restrict__ g,
                                                  const float* __restrict__ bt,
                                                  float invN, float2* __restrict__ ss) {
    int c = threadIdx.x;
    float s = 0.f, q = 0.f;
    #pragma unroll
    for (int k = 0; k < 64; k++) {
        s += part[k * 256 + c];
        q += part[k * 256 + 128 + c];
    }
    #pragma unroll
    for (int k = 0; k < 64; k++) {
        part[k * 256 + c] = 0.f;
        part[k * 256 + 128 + c] = 0.f;
    }
    float mu = s * invN;
    float var = q * invN - mu * mu;
    float scale = rsqrtf(var + 1e-5f) * g[c];
    ss[c] = make_float2(scale, bt[c] - mu * scale);
}

// ---------------- layer-2: 2 nodes per wave + aggregate + LayerNorm ----------------

__global__ __launch_bounds__(256) void k_agg2ln(const int* __restrict__ rowptr,
                                                const int* __restrict__ col,
                                                const short* __restrict__ Hb2,
                                                const unsigned short* __restrict__ w16,
                                                const float* __restrict__ b2,
                                                const float* __restrict__ lng,
                                                const float* __restrict__ lnb,
                                                float* __restrict__ out, int N) {
    int wv = threadIdx.x >> 6;
    int lane = threadIdx.x & 63;
    int nodeA = blockIdx.x * 8 + wv * 2;
    int nodeB = nodeA + 1;
    const unsigned short* H = (const unsigned short*)Hb2;
    bool vA = nodeA < N, vB = nodeB < N;
    int jA = 0, endA = 0, jB = 0, endB = 0;
    if (vA) { jA = rowptr[nodeA]; endA = rowptr[nodeA + 1]; }
    if (vB) { jB = rowptr[nodeB]; endB = rowptr[nodeB + 1]; }
    float sA = 0.f, aA = 0.f, sB = 0.f, aB = 0.f;

    while (jA + 4 <= endA && jB + 4 <= endB) {
        int c[8];
        #pragma unroll
        for (int k = 0; k < 4; k++) { c[k] = col[jA + k]; c[4 + k] = col[jB + k]; }
        float ww[8];
        unsigned short p[8];
        #pragma unroll
        for (int k = 0; k < 4; k++) {
            ww[k] = bf2f(w16[jA + k]);
            ww[4 + k] = bf2f(w16[jB + k]);
            p[k] = H[(c[k] << 6) + lane];
            p[4 + k] = H[(c[4 + k] << 6) + lane];
        }
        #pragma unroll
        for (int k = 0; k < 4; k++) {
            sA += ww[k];     aA += ww[k] * bf2f(p[k]);
            sB += ww[4 + k]; aB += ww[4 + k] * bf2f(p[4 + k]);
        }
        jA += 4; jB += 4;
    }
    for (; jA + 4 <= endA; jA += 4) {
        int c[4]; float ww[4]; unsigned short p[4];
        #pragma unroll
        for (int k = 0; k < 4; k++) c[k] = col[jA + k];
        #pragma unroll
        for (int k = 0; k < 4; k++) { ww[k] = bf2f(w16[jA + k]); p[k] = H[(c[k] << 6) + lane]; }
        #pragma unroll
        for (int k = 0; k < 4; k++) { sA += ww[k]; aA += ww[k] * bf2f(p[k]); }
    }
    for (; jA < endA; jA++) {
        int cc = col[jA];
        float wv2 = bf2f(w16[jA]);
        sA += wv2; aA += wv2 * bf2f(H[(cc << 6) + lane]);
    }
    for (; jB + 4 <= endB; jB += 4) {
        int c[4]; float ww[4]; unsigned short p[4];
        #pragma unroll
        for (int k = 0; k < 4; k++) c[k] = col[jB + k];
        #pragma unroll
        for (int k = 0; k < 4; k++) { ww[k] = bf2f(w16[jB + k]); p[k] = H[(c[k] << 6) + lane]; }
        #pragma unroll
        for (int k = 0; k < 4; k++) { sB += ww[k]; aB += ww[k] * bf2f(p[k]); }
    }
    for (; jB < endB; jB++) {
        int cc = col[jB];
        float wv2 = bf2f(w16[jB]);
        sB += wv2; aB += wv2 * bf2f(H[(cc << 6) + lane]);
    }

    if (vA) {
        float v = aA / (sA + 1e-16f) + b2[lane];
        float su = v, sq = v * v;
        #pragma unroll
        for (int off = 32; off; off >>= 1) {
            su += __shfl_xor(su, off, 64);
            sq += __shfl_xor(sq, off, 64);
        }
        float mu = su * (1.f / 64.f);
        float var = sq * (1.f / 64.f) - mu * mu;
        float r = rsqrtf(var + 1e-5f);
        out[(size_t)nodeA * 64 + lane] = (v - mu) * r * lng[lane] + lnb[lane];
    }
    if (vB) {
        float v = aB / (sB + 1e-16f) + b2[lane];
        float su = v, sq = v * v;
        #pragma unroll
        for (int off = 32; off; off >>= 1) {
            su += __shfl_xor(su, off, 64);
            sq += __shfl_xor(sq, off, 64);
        }
        float mu = su * (1.f / 64.f);
        float var = sq * (1.f / 64.f) - mu * mu;
        float r = rsqrtf(var + 1e-5f);
        out[(size_t)nodeB * 64 + lane] = (v - mu) * r * lng[lane] + lnb[lane];
    }
}

// ---------------- launch ----------------

extern "C" void kernel_launch(void* const* d_in, const int* in_sizes, int n_in,
                              void* d_out, int out_size, void* d_ws, size_t ws_size,
                              hipStream_t stream) {
    const float* x   = (const float*)d_in[0];
    const int*   ei  = (const int*)d_in[1];
    const float* W0  = (const float*)d_in[2];
    const float* as0 = (const float*)d_in[3];
    const float* ad0 = (const float*)d_in[4];
    const float* b0  = (const float*)d_in[5];
    const float* g0  = (const float*)d_in[6];
    const float* bt0 = (const float*)d_in[7];
    const float* W1  = (const float*)d_in[8];
    const float* as1 = (const float*)d_in[9];
    const float* ad1 = (const float*)d_in[10];
    const float* b1  = (const float*)d_in[11];
    const float* g1  = (const float*)d_in[12];
    const float* bt1 = (const float*)d_in[13];
    const float* W2  = (const float*)d_in[14];
    const float* as2 = (const float*)d_in[15];
    const float* ad2 = (const float*)d_in[16];
    const float* b2  = (const float*)d_in[17];
    const float* lng = (const float*)d_in[18];
    const float* lnb = (const float*)d_in[19];

    const int N = in_sizes[0] / 128;
    const int E = in_sizes[1] / 2;
    const int Etot = E + N;

    char* p = (char*)d_ws;
    auto carve = [&](size_t bytes) {
        void* q = (void*)p;
        p += (bytes + 255) & ~(size_t)255;
        return q;
    };
    short* Hb     = (short*)carve((size_t)N * 128 * 2);
    float* agg    = (float*)carve((size_t)N * 128 * 4);
    float* x1     = (float*)carve((size_t)N * 128 * 4);
    float* als    = (float*)carve((size_t)N * 8 * 4);
    float* ald    = (float*)carve((size_t)N * 8 * 4);
    int*   rowptr = (int*)carve((size_t)(N + 1) * 4);
    int*   cursor = (int*)carve((size_t)(N + 1) * 4);
    int*   deg    = (int*)carve((size_t)N * 4);
    int*   col    = (int*)carve((size_t)Etot * 4);
    int*   dstarr = (int*)carve((size_t)Etot * 4);
    unsigned short* w16 = (unsigned short*)carve((size_t)Etot * 8 * 2);
    float* part   = (float*)carve(64 * 256 * 4);
    float2* ss    = (float2*)carve(128 * 8);
    short* Wt0    = (short*)carve(144 * 128 * 2);
    short* Wt1    = (short*)carve(144 * 128 * 2);
    short* Wt2    = (short*)carve(80 * 128 * 2);
    int*   partial= (int*)carve(256 * 4);

    const float invN = 1.f / (float)N;
    const int eb = (E + N + 255) / 256;
    const int nsb = (N + SC - 1) / SC;

    hipMemsetAsync(deg, 0, (size_t)N * 4, stream);
    hipMemsetAsync(part, 0, 64 * 256 * 4, stream);
    k_count_wprep<<<eb, 256, 0, stream>>>(ei + E, E, N, deg, W0, W1, W2,
                                          as0, ad0, as1, ad1, as2, ad2, Wt0, Wt1, Wt2);
    k_scan1<<<nsb, 256, 0, stream>>>(deg, N, partial);
    k_scan2<<<1, 256, 0, stream>>>(partial, nsb);
    k_scan3<<<nsb, 256, 0, stream>>>(deg, N, Etot, partial, rowptr, cursor);
    k_fill<<<eb, 256, 0, stream>>>(ei, ei + E, E, N, cursor, col, dstarr);

    const int gb = (N + 127) / 128;
    const int ab = (N + 7) / 8;
    const int ewb8 = (Etot * 8 + 255) / 256;
    const int ewb1 = (Etot + 255) / 256;

    // ---- layer 0 ----
    k_gemm<128, false, false><<<gb, 256, 0, stream>>>(x, Wt0, Hb, nullptr, nullptr, nullptr,
                                                      als, ald, N);
    k_edgew8<<<ewb8, 256, 0, stream>>>(col, dstarr, als, ald, w16, Etot);
    k_agg<<<ab, 256, 0, stream>>>(rowptr, col, Hb, w16, b0, agg, part, N);
    k_bnreduce<<<1, 128, 0, stream>>>(part, g0, bt0, invN, ss);

    // ---- layer 1 (BN-apply fused into GEMM staging) ----
    k_gemm<128, true, true><<<gb, 256, 0, stream>>>(agg, Wt1, Hb, ss, x, x1, als, ald, N);
    k_edgew8<<<ewb8, 256, 0, stream>>>(col, dstarr, als, ald, w16, Etot);
    k_agg<<<ab, 256, 0, stream>>>(rowptr, col, Hb, w16, b1, agg, part, N);
    k_bnreduce<<<1, 128, 0, stream>>>(part, g1, bt1, invN, ss);

    // ---- layer 2 (BN-apply fused; x2 never materialized) ----
    k_gemm<64, true, false><<<gb, 256, 0, stream>>>(agg, Wt2, Hb, ss, x1, nullptr, als, ald, N);
    k_edgew1<<<ewb1, 256, 0, stream>>>(col, dstarr, als, ald, w16, Etot);
    k_agg2ln<<<ab, 256, 0, stream>>>(rowptr, col, Hb, w16, b2, lng, lnb, (float*)d_out, N);
}

// Round 10
// 494.959 us; speedup vs baseline: 1.1188x; 1.0299x over previous
//
#include <hip/hip_runtime.h>
#include <hip/hip_bf16.h>

#define LRELU(e) ((e) > 0.f ? (e) : 0.2f * (e))

typedef __attribute__((ext_vector_type(8))) short bf16x8;
typedef __attribute__((ext_vector_type(4))) float floatx4;

__device__ inline short f2bf(float f) {
    union { float f; unsigned u; } v; v.f = f;
    unsigned r = v.u + 0x7fffu + ((v.u >> 16) & 1u);
    return (short)(r >> 16);
}
__device__ inline float bflo(int p) {
    union { unsigned u; float f; } v; v.u = (unsigned)p << 16; return v.f;
}
__device__ inline float bfhi(int p) {
    union { unsigned u; float f; } v; v.u = (unsigned)p & 0xffff0000u; return v.f;
}
__device__ inline float bf2f(unsigned short s) {
    union { unsigned u; float f; } v; v.u = (unsigned)s << 16; return v.f;
}

// ---------------- CSR build + weight prep (incl. folded attention columns) ----------

__global__ void k_count_wprep(const int* __restrict__ dstE, int E, int N,
                              int* __restrict__ deg,
                              const float* __restrict__ W0, const float* __restrict__ W1,
                              const float* __restrict__ W2,
                              const float* __restrict__ as0, const float* __restrict__ ad0,
                              const float* __restrict__ as1, const float* __restrict__ ad1,
                              const float* __restrict__ as2, const float* __restrict__ ad2,
                              short* __restrict__ Wt0, short* __restrict__ Wt1,
                              short* __restrict__ Wt2) {
    int i = blockIdx.x * blockDim.x + threadIdx.x;
    if (i < E) atomicAdd(&deg[dstE[i]], 1);
    else if (i < E + N) atomicAdd(&deg[i - E], 1);

    if (i < 128 * 128) {
        int n = i >> 7, k = i & 127;
        Wt0[n * 128 + k] = f2bf(W0[k * 128 + n]);
        Wt1[n * 128 + k] = f2bf(W1[k * 128 + n]);
    } else if (i < 128 * 128 + 64 * 128) {
        int j = i - 128 * 128;
        int n = j >> 7, k = j & 127;
        Wt2[n * 128 + k] = f2bf(W2[k * 64 + n]);
    } else if (i < 128 * 128 + 64 * 128 + 128 * 8) {
        int j = i - (128 * 128 + 64 * 128);
        int k = j >> 3, h = j & 7;
        float s0 = 0.f, d0 = 0.f, s1 = 0.f, d1 = 0.f;
        #pragma unroll
        for (int d = 0; d < 16; d++) {
            float w0 = W0[k * 128 + h * 16 + d];
            float w1 = W1[k * 128 + h * 16 + d];
            s0 += w0 * as0[h * 16 + d];
            d0 += w0 * ad0[h * 16 + d];
            s1 += w1 * as1[h * 16 + d];
            d1 += w1 * ad1[h * 16 + d];
        }
        Wt0[(128 + h) * 128 + k] = f2bf(s0);
        Wt0[(136 + h) * 128 + k] = f2bf(d0);
        Wt1[(128 + h) * 128 + k] = f2bf(s1);
        Wt1[(136 + h) * 128 + k] = f2bf(d1);
    } else if (i < 128 * 128 + 64 * 128 + 128 * 8 + 128) {
        int k = i - (128 * 128 + 64 * 128 + 128 * 8);
        float s = 0.f, d = 0.f;
        #pragma unroll
        for (int dd = 0; dd < 64; dd++) {
            float w = W2[k * 64 + dd];
            s += w * as2[dd];
            d += w * ad2[dd];
        }
        Wt2[64 * 128 + k] = f2bf(s);
        Wt2[65 * 128 + k] = f2bf(d);
        #pragma unroll
        for (int r = 66; r < 80; r++) Wt2[r * 128 + k] = 0;
    }
}

constexpr int SC = 2048;

__global__ __launch_bounds__(256) void k_scan1(const int* __restrict__ deg, int N,
                                               int* __restrict__ partial) {
    int base = blockIdx.x * SC;
    int t = threadIdx.x;
    int s = 0;
    #pragma unroll
    for (int p = 0; p < SC / 256; p++) {
        int i = base + t + p * 256;
        if (i < N) s += deg[i];
    }
    #pragma unroll
    for (int off = 32; off; off >>= 1) s += __shfl_xor(s, off, 64);
    __shared__ int ws[4];
    int lane = t & 63, wid = t >> 6;
    if (lane == 0) ws[wid] = s;
    __syncthreads();
    if (t == 0) partial[blockIdx.x] = ws[0] + ws[1] + ws[2] + ws[3];
}

__global__ __launch_bounds__(256) void k_scan2(int* __restrict__ partial, int nb) {
    int t = threadIdx.x;
    int v = (t < nb) ? partial[t] : 0;
    int lane = t & 63, wid = t >> 6;
    int x = v;
    #pragma unroll
    for (int off = 1; off < 64; off <<= 1) {
        int y = __shfl_up(x, off, 64);
        if (lane >= off) x += y;
    }
    __shared__ int wsum[4];
    if (lane == 63) wsum[wid] = x;
    __syncthreads();
    int add = 0;
    for (int i = 0; i < wid; i++) add += wsum[i];
    if (t < nb) partial[t] = x + add - v;
}

__global__ __launch_bounds__(256) void k_scan3(const int* __restrict__ deg, int N, int Etot,
                                               const int* __restrict__ partial,
                                               int* __restrict__ rowptr,
                                               int* __restrict__ cursor) {
    int base = blockIdx.x * SC;
    int t = threadIdx.x;
    int i0 = base + t * 8;
    int v[8];
    int s = 0;
    #pragma unroll
    for (int p = 0; p < 8; p++) {
        int i = i0 + p;
        v[p] = (i < N) ? deg[i] : 0;
        s += v[p];
    }
    int lane = t & 63, wid = t >> 6;
    int x = s;
    #pragma unroll
    for (int off = 1; off < 64; off <<= 1) {
        int y = __shfl_up(x, off, 64);
        if (lane >= off) x += y;
    }
    __shared__ int wsum[4];
    if (lane == 63) wsum[wid] = x;
    __syncthreads();
    int add = 0;
    for (int i = 0; i < wid; i++) add += wsum[i];
    int excl = x - s + add + partial[blockIdx.x];
    #pragma unroll
    for (int p = 0; p < 8; p++) {
        int i = i0 + p;
        if (i < N) { rowptr[i] = excl; cursor[i] = excl; }
        excl += v[p];
    }
    if (blockIdx.x == 0 && t == 0) rowptr[N] = Etot;
}

__global__ void k_fill(const int* __restrict__ srcE, const int* __restrict__ dstE,
                       int E, int N, int* __restrict__ cursor, int* __restrict__ col,
                       int* __restrict__ dstarr) {
    int i = blockIdx.x * blockDim.x + threadIdx.x;
    if (i < E) {
        int d = dstE[i];
        int p = atomicAdd(&cursor[d], 1);
        col[p] = srcE[i];
        dstarr[p] = d;
    } else if (i < E + N) {
        int d = i - E;
        int p = atomicAdd(&cursor[d], 1);
        col[p] = d;
        dstarr[p] = d;
    }
}

// ---------------- MFMA bf16 GEMM + fused BN-apply; logits via augmented columns -------
// HASBN: X is bf16 'agg'; y = relu(X*scale+shift)+Xres. RESBF16: Xres is bf16.
// WRITEX: store y (bf16) to Xout.

template <int DOUT, bool HASBN, bool RESBF16, bool WRITEX>
__global__ __launch_bounds__(256) void k_gemm(const void* __restrict__ Xv,
                                              const short* __restrict__ Wt,
                                              short* __restrict__ Hout,
                                              const float2* __restrict__ ss,
                                              const void* __restrict__ Xresv,
                                              short* __restrict__ Xout,
                                              float* __restrict__ als,
                                              float* __restrict__ ald, int Nrows) {
    constexpr int KP = 136;
    constexpr int CT = DOUT / 16;
    constexpr int CTT = CT + 1;
    __shared__ __align__(16) short Xs[128 * KP];
    __shared__ __align__(16) short Ws[(DOUT + 16) * KP];

    const int tid = threadIdx.x;
    const int row0 = blockIdx.x * 128;

    {
        int c4 = tid & 31;
        int r0 = tid >> 5;
        float2 ssv[4];
        if (HASBN) {
            #pragma unroll
            for (int j = 0; j < 4; j++) ssv[j] = ss[c4 * 4 + j];
        }
        #pragma unroll
        for (int p = 0; p < 16; p++) {
            int r = r0 + p * 8;
            int grow = row0 + r;
            float vp[4] = {0.f, 0.f, 0.f, 0.f};
            if (grow < Nrows) {
                if (HASBN) {
                    short4 xb = *(const short4*)&((const short*)Xv)[(size_t)grow * 128 + c4 * 4];
                    vp[0] = bf2f((unsigned short)xb.x);
                    vp[1] = bf2f((unsigned short)xb.y);
                    vp[2] = bf2f((unsigned short)xb.z);
                    vp[3] = bf2f((unsigned short)xb.w);
                    float xr[4];
                    if (RESBF16) {
                        short4 rb = *(const short4*)&((const short*)Xresv)[(size_t)grow * 128 + c4 * 4];
                        xr[0] = bf2f((unsigned short)rb.x);
                        xr[1] = bf2f((unsigned short)rb.y);
                        xr[2] = bf2f((unsigned short)rb.z);
                        xr[3] = bf2f((unsigned short)rb.w);
                    } else {
                        float4 rf = *(const float4*)&((const float*)Xresv)[(size_t)grow * 128 + c4 * 4];
                        xr[0] = rf.x; xr[1] = rf.y; xr[2] = rf.z; xr[3] = rf.w;
                    }
                    #pragma unroll
                    for (int j = 0; j < 4; j++)
                        vp[j] = fmaxf(vp[j] * ssv[j].x + ssv[j].y, 0.f) + xr[j];
                } else {
                    float4 v = *(const float4*)&((const float*)Xv)[(size_t)grow * 128 + c4 * 4];
                    vp[0] = v.x; vp[1] = v.y; vp[2] = v.z; vp[3] = v.w;
                }
            }
            short4 b;
            b.x = f2bf(vp[0]); b.y = f2bf(vp[1]); b.z = f2bf(vp[2]); b.w = f2bf(vp[3]);
            if (WRITEX && grow < Nrows)
                *(short4*)&Xout[(size_t)grow * 128 + c4 * 4] = b;
            *(short4*)&Xs[r * KP + c4 * 4] = b;
        }
    }
    {
        constexpr int UNITS = (DOUT + 16) * 16;
        #pragma unroll
        for (int p = 0; p < UNITS / 256; p++) {
            int u = tid + p * 256;
            int n = u >> 4;
            int kc = (u & 15) * 8;
            bf16x8 v = *(const bf16x8*)&Wt[n * 128 + kc];
            *(bf16x8*)&Ws[n * KP + kc] = v;
        }
    }
    __syncthreads();

    const int lane = tid & 63;
    const int wv = tid >> 6;
    const int m0 = wv * 32;
    const int ln = lane & 15;
    const int quad = lane >> 4;

    floatx4 acc[2][CTT];
    #pragma unroll
    for (int mt = 0; mt < 2; mt++)
        #pragma unroll
        for (int ct = 0; ct < CTT; ct++) acc[mt][ct] = (floatx4){0.f, 0.f, 0.f, 0.f};

    #pragma unroll
    for (int ks = 0; ks < 4; ks++) {
        int ko = ks * 32 + quad * 8;
        bf16x8 a0 = *(const bf16x8*)&Xs[(m0 + ln) * KP + ko];
        bf16x8 a1 = *(const bf16x8*)&Xs[(m0 + 16 + ln) * KP + ko];
        #pragma unroll
        for (int ct = 0; ct < CTT; ct++) {
            bf16x8 b = *(const bf16x8*)&Ws[(ct * 16 + ln) * KP + ko];
            acc[0][ct] = __builtin_amdgcn_mfma_f32_16x16x32_bf16(a0, b, acc[0][ct], 0, 0, 0);
            acc[1][ct] = __builtin_amdgcn_mfma_f32_16x16x32_bf16(a1, b, acc[1][ct], 0, 0, 0);
        }
    }

    #pragma unroll
    for (int mt = 0; mt < 2; mt++) {
        #pragma unroll
        for (int r = 0; r < 4; r++) {
            int grow = row0 + m0 + mt * 16 + quad * 4 + r;
            if (grow < Nrows) {
                #pragma unroll
                for (int ct = 0; ct < CT; ct++)
                    Hout[(size_t)grow * DOUT + ct * 16 + ln] = f2bf(acc[mt][ct][r]);
                float aug = acc[mt][CT][r];
                if (DOUT == 128) {
                    if (ln < 8) als[grow * 8 + ln] = aug;
                    else        ald[grow * 8 + (ln - 8)] = aug;
                } else {
                    if (ln == 0) als[grow] = aug;
                    else if (ln == 1) ald[grow] = aug;
                }
            }
        }
    }
}

// ---------------- per-edge softmax weights (unnormalized, bf16) ----------------

__global__ void k_edgew8(const int* __restrict__ col, const int* __restrict__ dstarr,
                         const float* __restrict__ als, const float* __restrict__ ald,
                         unsigned short* __restrict__ w16, int Etot) {
    int i = blockIdx.x * blockDim.x + threadIdx.x;
    if (i >= Etot * 8) return;
    int j = i >> 3, h = i & 7;
    int s = col[j], d = dstarr[j];
    float e = als[s * 8 + h] + ald[d * 8 + h];
    e = LRELU(e);
    w16[i] = (unsigned short)f2bf(__expf(e));
}

__global__ void k_edgew1(const int* __restrict__ col, const int* __restrict__ dstarr,
                         const float* __restrict__ als, const float* __restrict__ ald,
                         unsigned short* __restrict__ w16, int Etot) {
    int j = blockIdx.x * blockDim.x + threadIdx.x;
    if (j >= Etot) return;
    float e = als[col[j]] + ald[dstarr[j]];
    e = LRELU(e);
    w16[j] = (unsigned short)f2bf(__expf(e));
}

// ---------------- aggregate: 2 nodes per wave + fused BN stats; bf16 output ----------

__global__ __launch_bounds__(256) void k_agg(const int* __restrict__ rowptr,
                                             const int* __restrict__ col,
                                             const short* __restrict__ Hb,
                                             const unsigned short* __restrict__ w16,
                                             const float* __restrict__ bias,
                                             short* __restrict__ out,
                                             float* __restrict__ part, int N) {
    __shared__ float red[8][128];
    int wv = threadIdx.x >> 6;
    int lane = threadIdx.x & 63;
    int nodeA = blockIdx.x * 8 + wv * 2;
    int nodeB = nodeA + 1;
    int h = lane >> 3;
    const int* Hi = (const int*)Hb;
    bool vA = nodeA < N, vB = nodeB < N;
    int jA = 0, endA = 0, jB = 0, endB = 0;
    if (vA) { jA = rowptr[nodeA]; endA = rowptr[nodeA + 1]; }
    if (vB) { jB = rowptr[nodeB]; endB = rowptr[nodeB + 1]; }
    float sA = 0.f, a0A = 0.f, a1A = 0.f;
    float sB = 0.f, a0B = 0.f, a1B = 0.f;

    while (jA + 4 <= endA && jB + 4 <= endB) {
        int c[8];
        #pragma unroll
        for (int k = 0; k < 4; k++) { c[k] = col[jA + k]; c[4 + k] = col[jB + k]; }
        float ww[8];
        int p[8];
        #pragma unroll
        for (int k = 0; k < 4; k++) {
            ww[k] = bf2f(w16[(jA + k) * 8 + h]);
            ww[4 + k] = bf2f(w16[(jB + k) * 8 + h]);
            p[k] = Hi[(c[k] << 6) + lane];
            p[4 + k] = Hi[(c[4 + k] << 6) + lane];
        }
        #pragma unroll
        for (int k = 0; k < 4; k++) {
            sA += ww[k];     a0A += ww[k] * bflo(p[k]);         a1A += ww[k] * bfhi(p[k]);
            sB += ww[4 + k]; a0B += ww[4 + k] * bflo(p[4 + k]); a1B += ww[4 + k] * bfhi(p[4 + k]);
        }
        jA += 4; jB += 4;
    }
    for (; jA + 4 <= endA; jA += 4) {
        int c[4]; float ww[4]; int p[4];
        #pragma unroll
        for (int k = 0; k < 4; k++) c[k] = col[jA + k];
        #pragma unroll
        for (int k = 0; k < 4; k++) { ww[k] = bf2f(w16[(jA + k) * 8 + h]); p[k] = Hi[(c[k] << 6) + lane]; }
        #pragma unroll
        for (int k = 0; k < 4; k++) { sA += ww[k]; a0A += ww[k] * bflo(p[k]); a1A += ww[k] * bfhi(p[k]); }
    }
    for (; jA < endA; jA++) {
        int cc = col[jA];
        float wv2 = bf2f(w16[jA * 8 + h]);
        int pp = Hi[(cc << 6) + lane];
        sA += wv2; a0A += wv2 * bflo(pp); a1A += wv2 * bfhi(pp);
    }
    for (; jB + 4 <= endB; jB += 4) {
        int c[4]; float ww[4]; int p[4];
        #pragma unroll
        for (int k = 0; k < 4; k++) c[k] = col[jB + k];
        #pragma unroll
        for (int k = 0; k < 4; k++) { ww[k] = bf2f(w16[(jB + k) * 8 + h]); p[k] = Hi[(c[k] << 6) + lane]; }
        #pragma unroll
        for (int k = 0; k < 4; k++) { sB += ww[k]; a0B += ww[k] * bflo(p[k]); a1B += ww[k] * bfhi(p[k]); }
    }
    for (; jB < endB; jB++) {
        int cc = col[jB];
        float wv2 = bf2f(w16[jB * 8 + h]);
        int pp = Hi[(cc << 6) + lane];
        sB += wv2; a0B += wv2 * bflo(pp); a1B += wv2 * bfhi(pp);
    }

    float bx = bias[2 * lane], by = bias[2 * lane + 1];
    float2 oA = make_float2(0.f, 0.f), oB = make_float2(0.f, 0.f);
    if (vA) {
        float inv = 1.f / (sA + 1e-16f);
        oA.x = a0A * inv + bx;
        oA.y = a1A * inv + by;
        int pack = (unsigned short)f2bf(oA.x) | ((unsigned)(unsigned short)f2bf(oA.y) << 16);
        ((int*)out)[(size_t)nodeA * 64 + lane] = pack;
    }
    if (vB) {
        float inv = 1.f / (sB + 1e-16f);
        oB.x = a0B * inv + bx;
        oB.y = a1B * inv + by;
        int pack = (unsigned short)f2bf(oB.x) | ((unsigned)(unsigned short)f2bf(oB.y) << 16);
        ((int*)out)[(size_t)nodeB * 64 + lane] = pack;
    }
    red[wv * 2][2 * lane] = oA.x;
    red[wv * 2][2 * lane + 1] = oA.y;
    red[wv * 2 + 1][2 * lane] = oB.x;
    red[wv * 2 + 1][2 * lane + 1] = oB.y;
    __syncthreads();
    if (threadIdx.x < 128) {
        int c = threadIdx.x;
        float s = 0.f, q = 0.f;
        #pragma unroll
        for (int r = 0; r < 8; r++) {
            float v = red[r][c];
            s += v;
            q += v * v;
        }
        float* slot = part + (blockIdx.x & 63) * 256;
        atomicAdd(&slot[c], s);
        atomicAdd(&slot[128 + c], q);
    }
}

// ---------------- reduce partials -> (scale, shift); re-zero part ----------------

__global__ __launch_bounds__(128) void k_bnreduce(float* __restrict__ part,
                                                  const float* __restrict__ g,
                                                  const float* __restrict__ bt,
                                                  float invN, float2* __restrict__ ss) {
    int c = threadIdx.x;
    float s = 0.f, q = 0.f;
    #pragma unroll
    for (int k = 0; k < 64; k++) {
        s += part[k * 256 + c];
        q += part[k * 256 + 128 + c];
    }
    #pragma unroll
    for (int k = 0; k < 64; k++) {
        part[k * 256 + c] = 0.f;
        part[k * 256 + 128 + c] = 0.f;
    }
    float mu = s * invN;
    float var = q * invN - mu * mu;
    float scale = rsqrtf(var + 1e-5f) * g[c];
    ss[c] = make_float2(scale, bt[c] - mu * scale);
}

// ---------------- layer-2: 2 nodes per wave + aggregate + LayerNorm ----------------

__global__ __launch_bounds__(256) void k_agg2ln(const int* __restrict__ rowptr,
                                                const int* __restrict__ col,
                                                const short* __restrict__ Hb2,
                                                const unsigned short* __restrict__ w16,
                                                const float* __restrict__ b2,
                                                const float* __restrict__ lng,
                                                const float* __restrict__ lnb,
                                                float* __restrict__ out, int N) {
    int wv = threadIdx.x >> 6;
    int lane = threadIdx.x & 63;
    int nodeA = blockIdx.x * 8 + wv * 2;
    int nodeB = nodeA + 1;
    const unsigned short* H = (const unsigned short*)Hb2;
    bool vA = nodeA < N, vB = nodeB < N;
    int jA = 0, endA = 0, jB = 0, endB = 0;
    if (vA) { jA = rowptr[nodeA]; endA = rowptr[nodeA + 1]; }
    if (vB) { jB = rowptr[nodeB]; endB = rowptr[nodeB + 1]; }
    float sA = 0.f, aA = 0.f, sB = 0.f, aB = 0.f;

    while (jA + 4 <= endA && jB + 4 <= endB) {
        int c[8];
        #pragma unroll
        for (int k = 0; k < 4; k++) { c[k] = col[jA + k]; c[4 + k] = col[jB + k]; }
        float ww[8];
        unsigned short p[8];
        #pragma unroll
        for (int k = 0; k < 4; k++) {
            ww[k] = bf2f(w16[jA + k]);
            ww[4 + k] = bf2f(w16[jB + k]);
            p[k] = H[(c[k] << 6) + lane];
            p[4 + k] = H[(c[4 + k] << 6) + lane];
        }
        #pragma unroll
        for (int k = 0; k < 4; k++) {
            sA += ww[k];     aA += ww[k] * bf2f(p[k]);
            sB += ww[4 + k]; aB += ww[4 + k] * bf2f(p[4 + k]);
        }
        jA += 4; jB += 4;
    }
    for (; jA + 4 <= endA; jA += 4) {
        int c[4]; float ww[4]; unsigned short p[4];
        #pragma unroll
        for (int k = 0; k < 4; k++) c[k] = col[jA + k];
        #pragma unroll
        for (int k = 0; k < 4; k++) { ww[k] = bf2f(w16[jA + k]); p[k] = H[(c[k] << 6) + lane]; }
        #pragma unroll
        for (int k = 0; k < 4; k++) { sA += ww[k]; aA += ww[k] * bf2f(p[k]); }
    }
    for (; jA < endA; jA++) {
        int cc = col[jA];
        float wv2 = bf2f(w16[jA]);
        sA += wv2; aA += wv2 * bf2f(H[(cc << 6) + lane]);
    }
    for (; jB + 4 <= endB; jB += 4) {
        int c[4]; float ww[4]; unsigned short p[4];
        #pragma unroll
        for (int k = 0; k < 4; k++) c[k] = col[jB + k];
        #pragma unroll
        for (int k = 0; k < 4; k++) { ww[k] = bf2f(w16[jB + k]); p[k] = H[(c[k] << 6) + lane]; }
        #pragma unroll
        for (int k = 0; k < 4; k++) { sB += ww[k]; aB += ww[k] * bf2f(p[k]); }
    }
    for (; jB < endB; jB++) {
        int cc = col[jB];
        float wv2 = bf2f(w16[jB]);
        sB += wv2; aB += wv2 * bf2f(H[(cc << 6) + lane]);
    }

    if (vA) {
        float v = aA / (sA + 1e-16f) + b2[lane];
        float su = v, sq = v * v;
        #pragma unroll
        for (int off = 32; off; off >>= 1) {
            su += __shfl_xor(su, off, 64);
            sq += __shfl_xor(sq, off, 64);
        }
        float mu = su * (1.f / 64.f);
        float var = sq * (1.f / 64.f) - mu * mu;
        float r = rsqrtf(var + 1e-5f);
        out[(size_t)nodeA * 64 + lane] = (v - mu) * r * lng[lane] + lnb[lane];
    }
    if (vB) {
        float v = aB / (sB + 1e-16f) + b2[lane];
        float su = v, sq = v * v;
        #pragma unroll
        for (int off = 32; off; off >>= 1) {
            su += __shfl_xor(su, off, 64);
            sq += __shfl_xor(sq, off, 64);
        }
        float mu = su * (1.f / 64.f);
        float var = sq * (1.f / 64.f) - mu * mu;
        float r = rsqrtf(var + 1e-5f);
        out[(size_t)nodeB * 64 + lane] = (v - mu) * r * lng[lane] + lnb[lane];
    }
}

// ---------------- launch ----------------

extern "C" void kernel_launch(void* const* d_in, const int* in_sizes, int n_in,
                              void* d_out, int out_size, void* d_ws, size_t ws_size,
                              hipStream_t stream) {
    const float* x   = (const float*)d_in[0];
    const int*   ei  = (const int*)d_in[1];
    const float* W0  = (const float*)d_in[2];
    const float* as0 = (const float*)d_in[3];
    const float* ad0 = (const float*)d_in[4];
    const float* b0  = (const float*)d_in[5];
    const float* g0  = (const float*)d_in[6];
    const float* bt0 = (const float*)d_in[7];
    const float* W1  = (const float*)d_in[8];
    const float* as1 = (const float*)d_in[9];
    const float* ad1 = (const float*)d_in[10];
    const float* b1  = (const float*)d_in[11];
    const float* g1  = (const float*)d_in[12];
    const float* bt1 = (const float*)d_in[13];
    const float* W2  = (const float*)d_in[14];
    const float* as2 = (const float*)d_in[15];
    const float* ad2 = (const float*)d_in[16];
    const float* b2  = (const float*)d_in[17];
    const float* lng = (const float*)d_in[18];
    const float* lnb = (const float*)d_in[19];

    const int N = in_sizes[0] / 128;
    const int E = in_sizes[1] / 2;
    const int Etot = E + N;

    char* p = (char*)d_ws;
    auto carve = [&](size_t bytes) {
        void* q = (void*)p;
        p += (bytes + 255) & ~(size_t)255;
        return q;
    };
    short* Hb     = (short*)carve((size_t)N * 128 * 2);
    short* aggb   = (short*)carve((size_t)N * 128 * 2);
    short* x1b    = (short*)carve((size_t)N * 128 * 2);
    float* als    = (float*)carve((size_t)N * 8 * 4);
    float* ald    = (float*)carve((size_t)N * 8 * 4);
    int*   rowptr = (int*)carve((size_t)(N + 1) * 4);
    int*   cursor = (int*)carve((size_t)(N + 1) * 4);
    // deg + part adjacent -> one memset
    const size_t degpad = ((size_t)N * 4 + 255) & ~(size_t)255;
    int*   deg    = (int*)carve(degpad);
    float* part   = (float*)carve(64 * 256 * 4);
    int*   col    = (int*)carve((size_t)Etot * 4);
    int*   dstarr = (int*)carve((size_t)Etot * 4);
    unsigned short* w16 = (unsigned short*)carve((size_t)Etot * 8 * 2);
    float2* ss    = (float2*)carve(128 * 8);
    short* Wt0    = (short*)carve(144 * 128 * 2);
    short* Wt1    = (short*)carve(144 * 128 * 2);
    short* Wt2    = (short*)carve(80 * 128 * 2);
    int*   partial= (int*)carve(256 * 4);

    const float invN = 1.f / (float)N;
    const int eb = (E + N + 255) / 256;
    const int nsb = (N + SC - 1) / SC;

    hipMemsetAsync(deg, 0, degpad + 64 * 256 * 4, stream);
    k_count_wprep<<<eb, 256, 0, stream>>>(ei + E, E, N, deg, W0, W1, W2,
                                          as0, ad0, as1, ad1, as2, ad2, Wt0, Wt1, Wt2);
    k_scan1<<<nsb, 256, 0, stream>>>(deg, N, partial);
    k_scan2<<<1, 256, 0, stream>>>(partial, nsb);
    k_scan3<<<nsb, 256, 0, stream>>>(deg, N, Etot, partial, rowptr, cursor);
    k_fill<<<eb, 256, 0, stream>>>(ei, ei + E, E, N, cursor, col, dstarr);

    const int gb = (N + 127) / 128;
    const int ab = (N + 7) / 8;
    const int ewb8 = (Etot * 8 + 255) / 256;
    const int ewb1 = (Etot + 255) / 256;

    // ---- layer 0 ----
    k_gemm<128, false, false, false><<<gb, 256, 0, stream>>>(x, Wt0, Hb, nullptr, nullptr,
                                                             nullptr, als, ald, N);
    k_edgew8<<<ewb8, 256, 0, stream>>>(col, dstarr, als, ald, w16, Etot);
    k_agg<<<ab, 256, 0, stream>>>(rowptr, col, Hb, w16, b0, aggb, part, N);
    k_bnreduce<<<1, 128, 0, stream>>>(part, g0, bt0, invN, ss);

    // ---- layer 1 (BN-apply fused into GEMM staging; agg/x1 bf16) ----
    k_gemm<128, true, false, true><<<gb, 256, 0, stream>>>(aggb, Wt1, Hb, ss, x, x1b,
                                                           als, ald, N);
    k_edgew8<<<ewb8, 256, 0, stream>>>(col, dstarr, als, ald, w16, Etot);
    k_agg<<<ab, 256, 0, stream>>>(rowptr, col, Hb, w16, b1, aggb, part, N);
    k_bnreduce<<<1, 128, 0, stream>>>(part, g1, bt1, invN, ss);

    // ---- layer 2 (BN-apply fused; bf16 residual; x2 never materialized) ----
    k_gemm<64, true, true, false><<<gb, 256, 0, stream>>>(aggb, Wt2, Hb, ss, x1b, nullptr,
                                                          als, ald, N);
    k_edgew1<<<ewb1, 256, 0, stream>>>(col, dstarr, als, ald, w16, Etot);
    k_agg2ln<<<ab, 256, 0, stream>>>(rowptr, col, Hb, w16, b2, lng, lnb, (float*)d_out, N);
}